// Round 4
// baseline (117.361 us; speedup 1.0000x reference)
//
#include <hip/hip_runtime.h>

#define NQ   12
#define DIM  4096
#define NL   4
#define BLK  256

typedef unsigned short u16;
typedef unsigned int   u32;

// ---------- compile-time GF(2) linear algebra for the CNOT-chain permutation ----------
struct L12 { u16 b[NQ]; };

static constexpr u32 lap(const L12& A, u32 x){ u32 r=0; for(int p=0;p<NQ;++p) if((x>>p)&1u) r^=A.b[p]; return r; }
static constexpr L12 lcomp(const L12& A, const L12& B){ L12 r{}; for(int p=0;p<NQ;++p) r.b[p]=(u16)lap(A,(u32)B.b[p]); return r; }
static constexpr L12 lident(){ L12 r{}; for(int p=0;p<NQ;++p) r.b[p]=(u16)(1u<<p); return r; }

static constexpr u32 applyT(u32 i){
  i ^= ((i>>0)&1u) << 11;                            // CNOT(11,0): bit11 ^= bit0
  for(int q=10;q>=0;--q){ int pc=11-q, pt=10-q; i ^= ((i>>pc)&1u) << pt; }
  return i;
}
static constexpr L12 lT(){ L12 t{}; for(int p=0;p<NQ;++p) t.b[p]=(u16)applyT(1u<<p); return t; }

static constexpr L12 linv(const L12& A){              // GF(2) Gauss-Jordan
  u16 v[NQ]; u16 u[NQ];
  for(int p=0;p<NQ;++p){ v[p]=A.b[p]; u[p]=(u16)(1u<<p); }
  for(int t=0;t<NQ;++t){
    int p=t; while(!((v[p]>>t)&1u)) ++p;
    u16 tv=v[p]; v[p]=v[t]; v[t]=tv; u16 tu=u[p]; u[p]=u[t]; u[t]=tu;
    for(int k=0;k<NQ;++k) if(k!=t && ((v[k]>>t)&1u)){ v[k]^=v[t]; u[k]^=u[t]; }
  }
  L12 r{}; for(int p=0;p<NQ;++p) r.b[p]=u[p]; return r;
}
static constexpr L12 ltr(const L12& A){
  L12 r{}; for(int p=0;p<NQ;++p) for(int q=0;q<NQ;++q) if((A.b[p]>>q)&1u) r.b[q]=(u16)(r.b[q]|(1u<<p));
  return r;
}

struct Tables {
  u16 cm[12][16];   // [step][combo] xor-offsets spanning the 4 gate masks
  u16 wg[12][4];    // [step][gate] parity mask: a0/a1 role selector
  u16 wexp[NQ];     // final <Z> parity masks: rows of (T^4)^{-T}
};

static constexpr Tables make_tables(){
  Tables tb{};
  const L12 T   = lT();
  const L12 Tit = ltr(linv(T));   // T^{-T}
  L12 A = lident();               // A_l = T^l
  L12 W = lident();               // W_l = A_l^{-T}
  for(int l=0;l<NL;++l){
    for(int g=0;g<3;++g){
      const int st = l*3+g;
      u16 mm[4]={0,0,0,0};
      for(int i=0;i<4;++i){ mm[i]=A.b[4*g+i]; tb.wg[st][i]=W.b[4*g+i]; }
      for(int c=0;c<16;++c){ u32 m=0; for(int i=0;i<4;++i) if((c>>i)&1) m^=mm[i]; tb.cm[st][c]=(u16)m; }
    }
    A = lcomp(A, T);
    W = lcomp(W, Tit);
  }
  for(int p=0;p<NQ;++p) tb.wexp[p]=W.b[p];
  return tb;
}

// ---------- LDS swizzle: slot = j ^ fold(j>>4), fold linear over GF(2) ----------
static constexpr u16 UIMG[12] = {1,2,4,8, 3,5,6,7, 9,10,11,13};
static constexpr u32 swz(u32 j){
  u32 f=0;
  for(int k=4;k<12;++k) if((j>>k)&1u) f ^= (u32)UIMG[k];
  return j ^ (f & 15u);
}

// ---------- generic GF(2) helpers ----------
static constexpr int par16(u16 v){ int n=0; for(int i=0;i<12;++i) n ^= (int)((v>>i)&1u); return n; }

struct Ech { u16 s[12]; };   // echelon: s[lb] has leading (highest) bit lb, or 0
static constexpr u16 ered(const Ech& e, u16 x){
  for(int it=0; it<13 && x; ++it){
    int lb=0; for(int b=0;b<12;++b) if((x>>b)&1u) lb=b;
    if(e.s[lb]) x=(u16)(x^e.s[lb]); else break;
  }
  return x;
}
static constexpr bool eadd(Ech& e, u16 x){
  x=ered(e,x); if(!x) return false;
  int lb=0; for(int b=0;b<12;++b) if((x>>b)&1u) lb=b;
  e.s[lb]=x; return true;
}

struct NullB { u16 v[12]; int n; };
// basis of { x : parity(rows[i]&x)=0 for all i }
static constexpr NullB nullspace(const u16* rows, int m){
  u16 rr[12]={}; int pc[12]={}; int nr=0;
  for(int i=0;i<m;++i){
    u16 x=rows[i];
    for(int j=0;j<nr;++j) if((x>>pc[j])&1u) x=(u16)(x^rr[j]);
    if(!x) continue;
    int lb=0; for(int b=0;b<12;++b) if((x>>b)&1u) lb=b;
    for(int j=0;j<nr;++j) if((rr[j]>>lb)&1u) rr[j]=(u16)(rr[j]^x);
    rr[nr]=x; pc[nr]=lb; ++nr;
  }
  NullB nb{};
  for(int f=0;f<12;++f){
    bool isp=false; for(int j=0;j<nr;++j) if(pc[j]==f) isp=true;
    if(isp) continue;
    u16 x=(u16)(1u<<f);
    for(int j=0;j<nr;++j) if((rr[j]>>f)&1u) x=(u16)(x|(1u<<pc[j]));
    nb.v[nb.n++]=x;
  }
  return nb;
}

// pick n vectors from (singles/pairs of) K's basis, independent of seed-span,
// greedily building rank-4 of swizzled bank-pair images (conflict floor)
static constexpr void pickN(const NullB& K, const u16* seed, int nseed, bool lowclear, u16* out, int n){
  Ech e{}; for(int i=0;i<nseed;++i) eadd(e, seed[i]);
  Ech bank{};
  for(int p=0;p<n;++p){
    u16 best=0; int bg=-1;
    for(int i=0;i<K.n;++i){
      u16 c=K.v[i]; if(lowclear) c=(u16)(c&0xFF0u); if(!c) continue;
      if(!ered(e,c)) continue;
      u16 img=(u16)(swz(c)&15u);
      int g=(img && ered(bank,img))?1:0;
      if(g>bg){ bg=g; best=c; }
      if(bg==1) break;
    }
    if(bg<1){
      for(int i=0;i<K.n && bg<1;++i) for(int j=i+1;j<K.n && bg<1;++j){
        u16 c=(u16)(K.v[i]^K.v[j]); if(lowclear) c=(u16)(c&0xFF0u); if(!c) continue;
        if(!ered(e,c)) continue;
        u16 img=(u16)(swz(c)&15u);
        int g=(img && ered(bank,img))?1:0;
        if(g>bg){ bg=g; best=c; }
      }
    }
    out[p]=best;
    if(best){ eadd(e,best); u16 img=(u16)(swz(best)&15u); if(img) eadd(bank,img); }
  }
}

// ---------- per-pair rep bases enabling barrier-free boundary (2p -> 2p+1) ----------
struct PairB { u16 rva[8]; u16 rvb[8]; bool ok; };

static constexpr PairB make_pair_basis(int a){
  const Tables tb = make_tables();
  const int b=a+1;
  u16 A[4], B[4], AB[8];
  for(int i=0;i<4;++i){ A[i]=tb.cm[a][1u<<i]; B[i]=tb.cm[b][1u<<i]; AB[i]=A[i]; AB[4+i]=B[i]; }
  PairB r{}; r.ok=true;
  NullB ann = nullspace(AB,8);          // functionals vanishing on span_a + span_b
  if(ann.n<2) r.ok=false;
  u16 f6 = r.ok?ann.v[0]:(u16)1, f7 = r.ok?ann.v[1]:(u16)2;
  u16 fr[2]={f6,f7};
  NullB K = nullspace(fr,2);            // 10-dim: ker f6 ∩ ker f7
  const bool lc = (a==0);               // step 0 reps must be 16-aligned (global float4 path)
  u16 v6=0, v7=0;                       // wave-bit vectors: dual pair to (f6,f7)
  for(u32 j=1;j<4096u && !(v6&&v7); ++j){
    u16 x=(u16)j; if(lc) x=(u16)(x&0xFF0u); if(!x) continue;
    int s6=par16((u16)(x&f6)), s7=par16((u16)(x&f7));
    if(s6==1&&s7==0&&v6==0) v6=x;
    else if(s6==0&&s7==1&&v7==0) v7=x;
  }
  if(!v6||!v7) r.ok=false;
  pickN(K, A, 4, lc,    r.rva, 6);
  pickN(K, B, 4, false, r.rvb, 6);
  r.rva[6]=v6; r.rva[7]=v7; r.rvb[6]=v6; r.rvb[7]=v7;
  if(r.ok){
    Ech ea{}; for(int i=0;i<4;++i) eadd(ea,A[i]);
    for(int k=0;k<6;++k){ if(!r.rva[k] || !eadd(ea,r.rva[k])) r.ok=false; }
    for(int i=0;i<4;++i) if(ered(ea,B[i])) r.ok=false;        // span_b covered by lane bits 0..5
    if(!eadd(ea,v6)) r.ok=false;
    if(!eadd(ea,v7)) r.ok=false;
    Ech eb{}; for(int i=0;i<4;++i) eadd(eb,B[i]);
    for(int k=0;k<8;++k){ if(!r.rvb[k] || !eadd(eb,r.rvb[k])) r.ok=false; }
    if(lc) for(int k=0;k<8;++k) if(r.rva[k]&15u) r.ok=false;
  }
  if(!r.ok){                            // fallback: independent bases, keep the barrier
    NullB full{}; full.n=12; for(int i=0;i<12;++i) full.v[i]=(u16)(1u<<i);
    pickN(full, A, 4, lc,    r.rva, 8);
    pickN(full, B, 4, false, r.rvb, 8);
  }
  return r;
}

static constexpr PairB PB0 = make_pair_basis(0);
static constexpr PairB PB1 = make_pair_basis(2);
static constexpr PairB PB2 = make_pair_basis(4);
static constexpr PairB PB3 = make_pair_basis(6);
static constexpr PairB PB4 = make_pair_basis(8);
static constexpr PairB PB5 = make_pair_basis(10);

struct Derived {
  u32 lane_c[12][8];  // tid bit k -> (swz(rv)<<3) | (role-parity nibble <<28)
  u32 smb[12][4];     // swz(cm[1<<i])<<3  (rep parity correction)
  u32 scmb[12][16];   // swz(cm[c])<<3     (coset member byte offsets)
  u32 g0lane[8];      // step 0: unswizzled contribution (16-aligned)
  u32 u11lane[8];     // step 11: unswizzled contribution
  u32 u11smb[4];      // step 11: unswizzled cm[1<<i]
  u16 pm[12];         // per-thread readout parity masks
  u16 mu[12];         // Walsh index per output q
  bool freeb[12];     // boundary after step st barrier-free?
};

static constexpr Derived make_derived(const PairB& p0,const PairB& p1,const PairB& p2,
                                      const PairB& p3,const PairB& p4,const PairB& p5){
  const Tables tb = make_tables();
  const PairB pb[6] = {p0,p1,p2,p3,p4,p5};
  Derived d{};
  for(int st=0; st<12; ++st){
    const PairB& P = pb[st/2];
    const u16* rv = (st%2==0)?P.rva:P.rvb;
    for(int k=0;k<8;++k){
      u32 nib=0;
      for(int i=0;i<4;++i) nib |= (u32)(par16((u16)(rv[k]&tb.wg[st][i]))&1)<<i;
      d.lane_c[st][k] = (swz((u32)rv[k])<<3) | (nib<<28);
      if(st==0)  d.g0lane[k]=(u32)rv[k];
      if(st==11) d.u11lane[k]=(u32)rv[k];
    }
    for(int i=0;i<4;++i)  d.smb[st][i]  = swz((u32)tb.cm[st][1u<<i])<<3;
    for(int c=0;c<16;++c) d.scmb[st][c] = swz((u32)tb.cm[st][c])<<3;
    if(st==11) for(int i=0;i<4;++i) d.u11smb[i]=(u32)tb.cm[11][1u<<i];
    d.freeb[st] = (st%2==0) ? pb[st/2].ok : false;
  }
  for(int q=0;q<12;++q){
    d.pm[q]=tb.wexp[11-q];
    u32 m=0;
    for(int i=0;i<4;++i) m |= (u32)(par16((u16)(tb.cm[11][1u<<i]&tb.wexp[11-q]))&1)<<i;
    d.mu[q]=(u16)m;
  }
  return d;
}

static constexpr Derived DVH = make_derived(PB0,PB1,PB2,PB3,PB4,PB5);
__device__ constexpr Derived DV = DVH;

// ---------- device code ----------
__device__ __forceinline__ void fence_free(){
  // same-wave write->read ordering only; no workgroup barrier needed
  asm volatile("s_waitcnt lgkmcnt(0)" ::: "memory");
}

// 4 commuting gates via 3-shear rotations (all-FMA), roles pre-aligned.
// out0 = cy*a0 - sy*a1 ; out1 = (cw + i*sw)*(sy*a0 + cy*a1)   (global phase dropped)
template<int ST, bool WITHW>
__device__ __forceinline__ void gates(float (&ar)[16], float (&ai)[16], const float4* __restrict__ gw){
#pragma unroll
  for(int i=0;i<4;++i){
    const float4 g = gw[ST*4+i];   // {tan(ty/4), sin(ty/2), tan(tz/2), sin(tz)}
#pragma unroll
    for(int c=0;c<16;++c){
      if((c>>i)&1) continue;
      const int c1 = c|(1<<i);
      float ur = fmaf(-g.x, ar[c1], ar[c]);
      float ui = fmaf(-g.x, ai[c1], ai[c]);
      float vr = fmaf( g.y, ur, ar[c1]);
      float vi = fmaf( g.y, ui, ai[c1]);
      ar[c] = fmaf(-g.x, vr, ur);
      ai[c] = fmaf(-g.x, vi, ui);
      if(WITHW){
        const float t = fmaf(-g.z, vi, vr);
        vi = fmaf( g.w, t, vi);
        vr = fmaf(-g.z, vi, t);
      }
      ar[c1]=vr; ai[c1]=vi;
    }
  }
}

template<int ST, bool WITHW>
__device__ __forceinline__ void mid_step(const u32* msk, char* lds, const float4* __restrict__ gw){
  u32 acc=0;
#pragma unroll
  for(int k=0;k<8;++k) acc ^= DV.lane_c[ST][k]&msk[k];
  const u32 nib = acc>>28;
  u32 base = acc & 0x0FFFFFFFu;
#pragma unroll
  for(int i=0;i<4;++i) base ^= DV.smb[ST][i] & (0u-((nib>>i)&1u));
  u32 ad[16]; float ar[16], ai[16];
#pragma unroll
  for(int c=0;c<16;++c){
    ad[c] = base ^ DV.scmb[ST][c];
    const float2 v = *(const float2*)(lds+ad[c]);
    ar[c]=v.x; ai[c]=v.y;
  }
  gates<ST,WITHW>(ar,ai,gw);
#pragma unroll
  for(int c=0;c<16;++c){ float2 v; v.x=ar[c]; v.y=ai[c]; *(float2*)(lds+ad[c])=v; }
}

template<int ST>
__device__ __forceinline__ void boundary(){
  if constexpr (DVH.freeb[ST]) fence_free(); else __syncthreads();
}

__global__ void prep_kernel(const float* __restrict__ w, float4* __restrict__ gw){
  const int t = threadIdx.x;
  if(t < NL*NQ){
    const int l=t/NQ, p=t%NQ, q=(NQ-1)-p;
    const float ty=w[(l*NQ+q)*2+0], tz=w[(l*NQ+q)*2+1];
    gw[t]=make_float4(tanf(0.25f*ty), sinf(0.5f*ty), tanf(0.5f*tz), sinf(tz));
  }
}

__global__ __launch_bounds__(BLK, 5) void qsim_kernel(const float* __restrict__ x,
                                                      const float4* __restrict__ gw,
                                                      float* __restrict__ out)
{
  __shared__ float2 st2[DIM];          // exactly 32768 B -> 5 blocks/CU
  char* lds = (char*)st2;
  const int tid = threadIdx.x;
  const int bb  = blockIdx.x;

  u32 msk[8];
#pragma unroll
  for(int k=0;k<8;++k) msk[k]=0u-((u32)(tid>>k)&1u);

  // ---- step 0: coset = 16 consecutive floats in global (reps 16-aligned) ----
  u32 rep0=0, acc0=0;
#pragma unroll
  for(int k=0;k<8;++k){ rep0 ^= DV.g0lane[k]&msk[k]; acc0 ^= DV.lane_c[0][k]&msk[k]; }
  const u32 base0 = acc0 & 0x0FFFFFFFu;   // nib == 0 at step 0

  float ar[16], ai[16];
  const float* xr = x + (size_t)bb*DIM + rep0;
#pragma unroll
  for(int s=0;s<4;++s){
    const float4 v = *reinterpret_cast<const float4*>(xr + 4*s);
    ar[4*s+0]=v.x; ar[4*s+1]=v.y; ar[4*s+2]=v.z; ar[4*s+3]=v.w;
    ai[4*s+0]=0.f; ai[4*s+1]=0.f; ai[4*s+2]=0.f; ai[4*s+3]=0.f;
  }
  gates<0,true>(ar,ai,gw);
#pragma unroll
  for(int c=0;c<16;++c){ float2 v; v.x=ar[c]; v.y=ai[c];
    *(float2*)(lds + (base0 ^ DV.scmb[0][c])) = v; }
  boundary<0>();

  mid_step<1,true >(msk,lds,gw); boundary<1>();
  mid_step<2,true >(msk,lds,gw); boundary<2>();
  mid_step<3,true >(msk,lds,gw); boundary<3>();
  mid_step<4,true >(msk,lds,gw); boundary<4>();
  mid_step<5,true >(msk,lds,gw); boundary<5>();
  mid_step<6,true >(msk,lds,gw); boundary<6>();
  mid_step<7,true >(msk,lds,gw); boundary<7>();
  mid_step<8,true >(msk,lds,gw); boundary<8>();
  mid_step<9,false>(msk,lds,gw); boundary<9>();   // last layer: RZ dropped
  mid_step<10,false>(msk,lds,gw); boundary<10>();

  // ---- step 11 + fused Walsh readout (no write-back) ----
  {
    u32 acc=0, urep=0;
#pragma unroll
    for(int k=0;k<8;++k){ acc ^= DV.lane_c[11][k]&msk[k]; urep ^= DV.u11lane[k]&msk[k]; }
    const u32 nib = acc>>28;
    u32 base = acc & 0x0FFFFFFFu;
#pragma unroll
    for(int i=0;i<4;++i){ const u32 mi=0u-((nib>>i)&1u); base ^= DV.smb[11][i]&mi; urep ^= DV.u11smb[i]&mi; }
#pragma unroll
    for(int c=0;c<16;++c){
      const float2 v = *(const float2*)(lds + (base ^ DV.scmb[11][c]));
      ar[c]=v.x; ai[c]=v.y;
    }
    gates<11,false>(ar,ai,gw);

    float pr[16];
#pragma unroll
    for(int c=0;c<16;++c) pr[c]=fmaf(ar[c],ar[c], ai[c]*ai[c]);
    // Walsh-Hadamard over the 4 combo bits: W[m] = sum_c (-1)^{popc(c&m)} pr[c]
#pragma unroll
    for(int b=1;b<16;b<<=1){
#pragma unroll
      for(int c=0;c<16;++c){
        if(c&b) continue;
        const float u=pr[c], v=pr[c|b];
        pr[c]=u+v; pr[c|b]=u-v;
      }
    }
    const float nrm = pr[0];
    float accq[12];
#pragma unroll
    for(int q=0;q<12;++q){
      const u32 sb = ((u32)__popc(urep & (u32)DV.pm[q]) & 1u)<<31;
      accq[q]=__uint_as_float(__float_as_uint(pr[DV.mu[q]])^sb);
    }
    float nrm2 = nrm;
#pragma unroll
    for(int o=32;o;o>>=1){
      nrm2 += __shfl_xor(nrm2,o);
#pragma unroll
      for(int q=0;q<12;++q) accq[q]+=__shfl_xor(accq[q],o);
    }
    __syncthreads();                      // all waves done reading step 11
    float* wredf = (float*)lds;           // alias reduction buffer into state LDS
    const int wid=tid>>6;
    if((tid&63)==0){
#pragma unroll
      for(int q=0;q<12;++q) wredf[wid*13+q]=accq[q];
      wredf[wid*13+12]=nrm2;
    }
    __syncthreads();
    if(tid<NQ){
      const float s0=wredf[0*13+tid]+wredf[1*13+tid]+wredf[2*13+tid]+wredf[3*13+tid];
      const float sn=wredf[0*13+12]+wredf[1*13+12]+wredf[2*13+12]+wredf[3*13+12];
      out[(size_t)bb*NQ+tid]=s0/sn;
    }
  }
}

extern "C" void kernel_launch(void* const* d_in, const int* in_sizes, int n_in,
                              void* d_out, int out_size, void* d_ws, size_t ws_size,
                              hipStream_t stream) {
  const float* x = (const float*)d_in[0];
  const float* w = (const float*)d_in[1];
  float* out = (float*)d_out;
  float4* gw = (float4*)d_ws;
  const int B = in_sizes[0] / DIM;
  prep_kernel<<<1, 64, 0, stream>>>(w, gw);
  qsim_kernel<<<B, BLK, 0, stream>>>(x, gw, out);
}

// Round 5
// 106.993 us; speedup vs baseline: 1.0969x; 1.0969x over previous
//
#include <hip/hip_runtime.h>

#define NQ   12
#define DIM  4096
#define NL   4
#define BLK  256

typedef unsigned short u16;
typedef unsigned int   u32;
typedef float f2 __attribute__((ext_vector_type(2)));

// ---------- compile-time GF(2) linear algebra for the CNOT-chain permutation ----------
struct L12 { u16 b[NQ]; };

static constexpr u32 lap(const L12& A, u32 x){ u32 r=0; for(int p=0;p<NQ;++p) if((x>>p)&1u) r^=A.b[p]; return r; }
static constexpr L12 lcomp(const L12& A, const L12& B){ L12 r{}; for(int p=0;p<NQ;++p) r.b[p]=(u16)lap(A,(u32)B.b[p]); return r; }
static constexpr L12 lident(){ L12 r{}; for(int p=0;p<NQ;++p) r.b[p]=(u16)(1u<<p); return r; }

static constexpr u32 applyT(u32 i){
  i ^= ((i>>0)&1u) << 11;                            // CNOT(11,0): bit11 ^= bit0
  for(int q=10;q>=0;--q){ int pc=11-q, pt=10-q; i ^= ((i>>pc)&1u) << pt; }
  return i;
}
static constexpr L12 lT(){ L12 t{}; for(int p=0;p<NQ;++p) t.b[p]=(u16)applyT(1u<<p); return t; }

static constexpr L12 linv(const L12& A){              // GF(2) Gauss-Jordan
  u16 v[NQ]; u16 u[NQ];
  for(int p=0;p<NQ;++p){ v[p]=A.b[p]; u[p]=(u16)(1u<<p); }
  for(int t=0;t<NQ;++t){
    int p=t; while(!((v[p]>>t)&1u)) ++p;
    u16 tv=v[p]; v[p]=v[t]; v[t]=tv; u16 tu=u[p]; u[p]=u[t]; u[t]=tu;
    for(int k=0;k<NQ;++k) if(k!=t && ((v[k]>>t)&1u)){ v[k]^=v[t]; u[k]^=u[t]; }
  }
  L12 r{}; for(int p=0;p<NQ;++p) r.b[p]=u[p]; return r;
}
static constexpr L12 ltr(const L12& A){
  L12 r{}; for(int p=0;p<NQ;++p) for(int q=0;q<NQ;++q) if((A.b[p]>>q)&1u) r.b[q]=(u16)(r.b[q]|(1u<<p));
  return r;
}
static constexpr int cpop(u32 v){ int n=0; while(v){ n+=(int)(v&1u); v>>=1; } return n; }

struct Tables {
  u16 cm[12][16];   // [step][combo] xor-offsets spanning the 4 gate masks
  u16 wg[12][4];    // [step][gate] parity mask: a0/a1 role selector
  u16 sp[12][4];    // [step] sorted pivot bit positions
  u16 wexp[NQ];     // final <Z> parity masks: rows of (T^4)^{-T}
};

static constexpr Tables make_tables(){
  Tables tb{};
  const L12 T   = lT();
  const L12 Tit = ltr(linv(T));   // T^{-T}
  L12 A = lident();               // A_l = T^l   (stored_index = A_l(true_index))
  L12 W = lident();               // W_l = A_l^{-T}
  for(int l=0;l<NL;++l){
    for(int g=0;g<3;++g){
      const int st = l*3+g;
      u16 mm[4]={0,0,0,0};
      for(int i=0;i<4;++i){ mm[i]=A.b[4*g+i]; tb.wg[st][i]=W.b[4*g+i]; }
      u32 ech[4]={0,0,0,0}; int piv[4]={0,0,0,0};
      for(int i=0;i<4;++i){
        u32 v=mm[i];
        for(int k=0;k<i;++k) if((v>>piv[k])&1u) v^=ech[k];
        int t2=11; while(!((v>>t2)&1u)) --t2;
        piv[i]=t2; ech[i]=v;
      }
      for(int a2=0;a2<4;++a2) for(int b2=a2+1;b2<4;++b2)
        if(piv[b2]<piv[a2]){ int tt=piv[a2]; piv[a2]=piv[b2]; piv[b2]=tt; }
      for(int i=0;i<4;++i) tb.sp[st][i]=(u16)piv[i];
      for(int c=0;c<16;++c){ u32 m=0; for(int i=0;i<4;++i) if((c>>i)&1) m^=mm[i]; tb.cm[st][c]=(u16)m; }
    }
    A = lcomp(A, T);
    W = lcomp(W, Tit);
  }
  for(int p=0;p<NQ;++p) tb.wexp[p]=W.b[p];
  return tb;
}

__device__ constexpr Tables TB = make_tables();

// ---------- LDS swizzle: slot = j ^ fold(j>>4), fold linear over GF(2) ----------
static constexpr u16 UIMG[12] = {1,2,4,8, 3,5,6,7, 9,10,11,13};

static constexpr u32 swz(u32 j){
  u32 f=0;
  for(int k=4;k<12;++k) if((j>>k)&1u) f ^= (u32)UIMG[k];
  return j ^ (f & 15u);
}

struct Derived {
  u32 lane_c[12][8];  // tid bit k -> (swz(1<<pos)<<3) | (role-parity nibble <<28)
  u32 smb[12][4];     // swz(cm[1<<i])<<3  (rep parity correction, swizzled)
  u32 scmb[12][16];   // swz(cm[c])<<3     (coset member byte offsets)
  u32 g0lane[8];      // step 0: unswizzled element-index contribution of tid bit k
  u32 u11lane[8];     // step 11: unswizzled index contribution of tid bit k
  u32 u11smb[4];      // step 11: unswizzled cm[1<<i]
  u16 pm[12];         // wexp[11-q]: per-thread parity mask on unswizzled rep
  u16 mu[12];         // Walsh index per output q
};

static constexpr Derived make_derived(){
  const Tables tb = make_tables();
  Derived d{};
  for(int st=0; st<12; ++st){
    bool isp[12]={false,false,false,false,false,false,false,false,false,false,false,false};
    for(int i=0;i<4;++i) isp[tb.sp[st][i]]=true;
    int np[8]; int nn=0;
    for(int p=0;p<12;++p) if(!isp[p]) np[nn++]=p;
    // choose 6 of 8 non-pivot positions for lane bits s.t. their GF(2)^4
    // bank-pair images have rank 4 -> exactly 4 lanes/bank-pair (b64 floor)
    int best=-1;
    for(int ms=0; ms<256; ++ms){
      int pc=0; for(int k=0;k<8;++k) pc+=(ms>>k)&1;
      if(pc!=6) continue;
      u16 bas[4]={0,0,0,0}; int r=0;
      for(int k=0;k<8;++k){
        if(!((ms>>k)&1)) continue;
        u16 x=(u16)(UIMG[np[k]]&15);
        while(x){
          int hb=3; while(!((x>>hb)&1)) --hb;
          if(bas[hb]) x=(u16)(x^bas[hb]);
          else { bas[hb]=x; ++r; x=0; }
        }
      }
      if(r==4){ best=ms; break; }
    }
    if(best<0) best=0x3F;
    int pos[8]; int lo=0, hi=6;
    for(int k=0;k<8;++k){ if((best>>k)&1) pos[lo++]=np[k]; else pos[hi++]=np[k]; }
    for(int k=0;k<8;++k){
      const u32 addr = swz(1u<<pos[k])<<3;
      u32 nib=0;
      for(int i=0;i<4;++i) nib |= (u32)((tb.wg[st][i]>>pos[k])&1u)<<i;
      d.lane_c[st][k] = addr | (nib<<28);
      if(st==0)  d.g0lane[k]  = 1u<<pos[k];
      if(st==11) d.u11lane[k] = 1u<<pos[k];
    }
    for(int i=0;i<4;++i)  d.smb[st][i]  = swz((u32)tb.cm[st][1<<i])<<3;
    for(int c=0;c<16;++c) d.scmb[st][c] = swz((u32)tb.cm[st][c])<<3;
    if(st==11) for(int i=0;i<4;++i) d.u11smb[i] = (u32)tb.cm[11][1<<i];
  }
  for(int q=0;q<12;++q){
    d.pm[q] = tb.wexp[11-q];
    u32 m=0;
    for(int i=0;i<4;++i) m |= (u32)(cpop((u32)tb.cm[11][1u<<i] & (u32)tb.wexp[11-q])&1)<<i;
    d.mu[q]=(u16)m;
  }
  return d;
}

__device__ constexpr Derived DV = make_derived();

// ---------- 4 commuting gates via 3-shear rotations, packed over (re,im) ----------
// RY shear coefficients identical on re/im -> v_pk_fma_f32; RZ phase is
// cross-component (3 scalar FMAs). Global phase dropped (|amp|^2 readout).
template<int ST, bool WITHW>
__device__ __forceinline__ void gates(f2 (&a)[16], const float4* __restrict__ gw){
#pragma unroll
  for(int i=0;i<4;++i){
    const float4 g = gw[ST*4+i];   // {tan(ty/4), sin(ty/2), tan(tz/2), sin(tz)}
    const f2 mt = {-g.x, -g.x};
    const f2 sy = { g.y,  g.y};
#pragma unroll
    for(int c=0;c<16;++c){
      if((c>>i)&1) continue;
      const int c1 = c|(1<<i);
      f2 u = __builtin_elementwise_fma(mt, a[c1], a[c]);   // u  = a0 - t*a1
      f2 v = __builtin_elementwise_fma(sy, u, a[c1]);      // a1'= a1 + s*u
      a[c] = __builtin_elementwise_fma(mt, v, u);          // a0'= u  - t*a1'
      if(WITHW){                                           // rotate (v.x,v.y) by +tz
        const float t = fmaf(-g.z, v.y, v.x);
        v.y = fmaf( g.w, t, v.y);
        v.x = fmaf(-g.z, v.y, t);
      }
      a[c1]=v;
    }
  }
}

template<int ST, bool WITHW>
__device__ __forceinline__ void mid_step(const u32* msk, char* lds, const float4* __restrict__ gw){
  u32 acc=0;
#pragma unroll
  for(int k=0;k<8;++k) acc ^= DV.lane_c[ST][k]&msk[k];
  const u32 nib = acc>>28;
  u32 base = acc & 0x0FFFFFFFu;
#pragma unroll
  for(int i=0;i<4;++i) base ^= DV.smb[ST][i] & (0u-((nib>>i)&1u));
  u32 ad[16]; f2 a[16];
#pragma unroll
  for(int c=0;c<16;++c){
    ad[c] = base ^ DV.scmb[ST][c];
    a[c] = *(const f2*)(lds+ad[c]);
  }
  gates<ST,WITHW>(a,gw);
#pragma unroll
  for(int c=0;c<16;++c){ *(f2*)(lds+ad[c]) = a[c]; }
  __syncthreads();
}

__global__ void prep_kernel(const float* __restrict__ w, float4* __restrict__ gw){
  const int t = threadIdx.x;
  if(t < NL*NQ){
    const int l=t/NQ, p=t%NQ, q=(NQ-1)-p;
    const float ty=w[(l*NQ+q)*2+0], tz=w[(l*NQ+q)*2+1];
    gw[t]=make_float4(tanf(0.25f*ty), sinf(0.5f*ty), tanf(0.5f*tz), sinf(tz));
  }
}

__global__ __launch_bounds__(BLK, 5) void qsim_kernel(const float* __restrict__ x,
                                                      const float4* __restrict__ gw,
                                                      float* __restrict__ out)
{
  __shared__ f2 st2[DIM];              // exactly 32768 B
  char* lds = (char*)st2;
  const int tid = threadIdx.x;
  const int bb  = blockIdx.x;

  u32 msk[8];
#pragma unroll
  for(int k=0;k<8;++k) msk[k]=0u-((u32)(tid>>k)&1u);

  // ---- step 0: masks are bits 0..3 -> coset = 16 consecutive floats in global ----
  u32 rep0=0, acc0=0;
#pragma unroll
  for(int k=0;k<8;++k){ rep0 ^= DV.g0lane[k]&msk[k]; acc0 ^= DV.lane_c[0][k]&msk[k]; }
  const u32 base0 = acc0 & 0x0FFFFFFFu;   // nib == 0 at step 0

  f2 a[16];
  const float* xr = x + (size_t)bb*DIM + rep0;
#pragma unroll
  for(int s=0;s<4;++s){
    const float4 v = *reinterpret_cast<const float4*>(xr + 4*s);
    a[4*s+0]=(f2){v.x,0.f}; a[4*s+1]=(f2){v.y,0.f};
    a[4*s+2]=(f2){v.z,0.f}; a[4*s+3]=(f2){v.w,0.f};
  }
  gates<0,true>(a,gw);
#pragma unroll
  for(int c=0;c<16;++c){ *(f2*)(lds + (base0 ^ DV.scmb[0][c])) = a[c]; }
  __syncthreads();

  // ---- steps 1..10: LDS round trips ----
  mid_step<1,true >(msk,lds,gw);
  mid_step<2,true >(msk,lds,gw);
  mid_step<3,true >(msk,lds,gw);
  mid_step<4,true >(msk,lds,gw);
  mid_step<5,true >(msk,lds,gw);
  mid_step<6,true >(msk,lds,gw);
  mid_step<7,true >(msk,lds,gw);
  mid_step<8,true >(msk,lds,gw);
  mid_step<9,false>(msk,lds,gw);     // last layer: RZ phase dropped (|amp|^2 readout)
  mid_step<10,false>(msk,lds,gw);

  // ---- step 11 + fused Walsh readout (no write-back) ----
  {
    u32 acc=0, urep=0;
#pragma unroll
    for(int k=0;k<8;++k){ acc ^= DV.lane_c[11][k]&msk[k]; urep ^= DV.u11lane[k]&msk[k]; }
    const u32 nib = acc>>28;
    u32 base = acc & 0x0FFFFFFFu;
#pragma unroll
    for(int i=0;i<4;++i){ const u32 mi=0u-((nib>>i)&1u); base ^= DV.smb[11][i]&mi; urep ^= DV.u11smb[i]&mi; }
#pragma unroll
    for(int c=0;c<16;++c){
      a[c] = *(const f2*)(lds + (base ^ DV.scmb[11][c]));
    }
    gates<11,false>(a,gw);

    float pr[16];
#pragma unroll
    for(int c=0;c<16;++c) pr[c]=fmaf(a[c].x,a[c].x, a[c].y*a[c].y);
    // Walsh-Hadamard over the 4 combo bits: W[m] = sum_c (-1)^{popc(c&m)} pr[c]
#pragma unroll
    for(int b=1;b<16;b<<=1){
#pragma unroll
      for(int c=0;c<16;++c){
        if(c&b) continue;
        const float u=pr[c], v=pr[c|b];
        pr[c]=u+v; pr[c|b]=u-v;
      }
    }
    float accq[12];
#pragma unroll
    for(int q=0;q<12;++q){
      const u32 sb = ((u32)__popc(urep & (u32)DV.pm[q]) & 1u)<<31;
      accq[q]=__uint_as_float(__float_as_uint(pr[DV.mu[q]])^sb);
    }
    float nrm2 = pr[0];
#pragma unroll
    for(int o=32;o;o>>=1){
      nrm2 += __shfl_xor(nrm2,o);
#pragma unroll
      for(int q=0;q<12;++q) accq[q]+=__shfl_xor(accq[q],o);
    }
    __syncthreads();                      // all waves done reading step 11
    float* wredf = (float*)lds;           // alias reduction buffer into state LDS
    const int wid=tid>>6;
    if((tid&63)==0){
#pragma unroll
      for(int q=0;q<12;++q) wredf[wid*13+q]=accq[q];
      wredf[wid*13+12]=nrm2;
    }
    __syncthreads();
    if(tid<NQ){
      const float s0=wredf[0*13+tid]+wredf[1*13+tid]+wredf[2*13+tid]+wredf[3*13+tid];
      const float sn=wredf[0*13+12]+wredf[1*13+12]+wredf[2*13+12]+wredf[3*13+12];
      out[(size_t)bb*NQ+tid]=s0/sn;
    }
  }
}

extern "C" void kernel_launch(void* const* d_in, const int* in_sizes, int n_in,
                              void* d_out, int out_size, void* d_ws, size_t ws_size,
                              hipStream_t stream) {
  const float* x = (const float*)d_in[0];
  const float* w = (const float*)d_in[1];
  float* out = (float*)d_out;
  float4* gw = (float4*)d_ws;
  const int B = in_sizes[0] / DIM;
  prep_kernel<<<1, 64, 0, stream>>>(w, gw);
  qsim_kernel<<<B, BLK, 0, stream>>>(x, gw, out);
}